// Round 1
// baseline (138.879 us; speedup 1.0000x reference)
//
#include <hip/hip_runtime.h>
#include <cfloat>

typedef __bf16 bf16x8 __attribute__((ext_vector_type(8)));
typedef unsigned short ushort8 __attribute__((ext_vector_type(8)));
typedef float f32x16 __attribute__((ext_vector_type(16)));

#define S_SLICES 4   // 96 x 4 x 2 = 768 blocks = 3/CU, fully resident

// fp32 -> bf16 bits, round-to-nearest-even
static __device__ __forceinline__ unsigned short f2bf(float x) {
    unsigned u = __float_as_uint(x);
    return (unsigned short)((u + 0x7FFFu + ((u >> 16) & 1u)) >> 16);
}
static __device__ __forceinline__ float bfbits2f(unsigned short h) {
    return __uint_as_float(((unsigned)h) << 16);
}

// Per point, build TWO 16-element K-vectors (verified round 7/8):
//  row vec: [-2hx,-2hy,-2hz, -2hx,-2hy,-2hz, -2lx,-2ly,-2lz, s1,s2,s3, 1,1,1, 0]
//  col vec: [ hx,  hy,  hz,   lx,  ly,  lz,   hx,  hy,  hz,  1,1,1, t1,t2,t3, 0]
//  => sum_k row[k]*col[k] = nrmRow + nrmCol - 2(hh+hl+lh) ~= d2 (err ~1e-4).
// Fragment storage: frag[tile*64 + q*32 + l5], point = tile*32+l5, k = q*8+j.
// Pad points get nrm=1e30 -> never win a min.
__global__ __launch_bounds__(256) void prep_kernel(
    const float* __restrict__ A, const float* __restrict__ B,
    ushort8* __restrict__ RFA, ushort8* __restrict__ CFA,
    ushort8* __restrict__ RFB, ushort8* __restrict__ CFB,
    float* __restrict__ hdr, unsigned* __restrict__ rtc,
    int n, int m, int RTn, int RTm)
{
    const int i = blockIdx.x * 256 + threadIdx.x;
    if (i < 8) hdr[i] = 0.f;
    const int maxRT = (RTn > RTm) ? RTn : RTm;
    if (i < 2 * maxRT) rtc[i] = 0u;          // per-rt slice-completion tickets
    const unsigned short one = 0x3F80;

#pragma unroll
    for (int side = 0; side < 2; ++side) {
        const int cntPts = side ? RTm * 32 : RTn * 32;
        if (i >= cntPts) continue;
        const float* P = side ? B : A;
        const int lim = side ? m : n;
        ushort8* RF = side ? RFB : RFA;
        ushort8* CF = side ? CFB : CFA;

        float x = 0.f, y = 0.f, z = 0.f, nrm = 1e30f;
        if (i < lim) { x = P[3*i]; y = P[3*i+1]; z = P[3*i+2];
                       nrm = fmaf(x, x, fmaf(y, y, z * z)); }
        const unsigned short hx = f2bf(x), hy = f2bf(y), hz = f2bf(z);
        const unsigned short lx = f2bf(x - bfbits2f(hx)),
                             ly = f2bf(y - bfbits2f(hy)),
                             lz = f2bf(z - bfbits2f(hz));
        const unsigned short nhx = f2bf(-2.f * bfbits2f(hx)),
                             nhy = f2bf(-2.f * bfbits2f(hy)),
                             nhz = f2bf(-2.f * bfbits2f(hz));
        const unsigned short nlx = f2bf(-2.f * bfbits2f(lx)),
                             nly = f2bf(-2.f * bfbits2f(ly)),
                             nlz = f2bf(-2.f * bfbits2f(lz));
        float r = nrm;
        const unsigned short s1 = f2bf(r); r -= bfbits2f(s1);
        const unsigned short s2 = f2bf(r); r -= bfbits2f(s2);
        const unsigned short s3 = f2bf(r);

        const int t = i >> 5, l5 = i & 31;
        ushort8 rq0 = { nhx, nhy, nhz, nhx, nhy, nhz, nlx, nly };
        ushort8 rq1 = { nlz, s1, s2, s3, one, one, one, 0 };
        RF[t * 64 + l5]      = rq0;
        RF[t * 64 + 32 + l5] = rq1;
        ushort8 cq0 = { hx, hy, hz, lx, ly, lz, hx, hy };
        ushort8 cq1 = { hz, one, one, one, s1, s2, s3, 0 };
        CF[t * 64 + l5]      = cq0;
        CF[t * 64 + 32 + l5] = cq1;
    }
}

#define MINC(C)                                             \
    _Pragma("unroll")                                       \
    for (int r = 0; r < 16; ++r) macc[r] = fminf(macc[r], (C)[r]);

// z=0: rows=A vs cols=B -> sbuf side 0 ("mins"); z=1: transposed ("mins_seeds").
// Round 8 lesson: __launch_bounds__(256,4) keeps C in VGPRs (no accvgpr
// shuttling). Round 10 lesson: mfma(b) right after b's load exposes full
// vmem latency per tile -> 4-deep static prefetch queue (q0..q3) + 2 C in
// flight so every vmcnt wait has retired by use.
// Round 11: finalize fused in via per-rt tickets (launch-overhead theory):
// the 4th slice-wave of each rt does the cross-slice min + sqrt + sums inline;
// a global ticket emits the scalars. __threadfence() (agent-scope, wbl2+inv)
// before each ticket handles cross-XCD L2 non-coherence — same proven pattern
// as the old finalize kernel. No spin-waits -> no deadlock mode.
__global__ __launch_bounds__(256, 4) void pairmin_kernel(
    const bf16x8* __restrict__ RFA, const bf16x8* __restrict__ CFA,
    const bf16x8* __restrict__ RFB, const bf16x8* __restrict__ CFB,
    float* __restrict__ sbuf, unsigned* __restrict__ rtc,
    float* __restrict__ hdr, float* __restrict__ out,
    int n, int m, int RTn, int RTm)
{
    const int lane = threadIdx.x & 63;
    const int wave = threadIdx.x >> 6;
    const int maxRT = (RTn > RTm) ? RTn : RTm;

    const bf16x8* RF; const bf16x8* CF; float* sb0;
    int rtCount, ctCount, stride, lim;
    if (blockIdx.z == 0) { RF = RFA; CF = CFB; rtCount = RTn; ctCount = RTm;
                           sb0 = sbuf; stride = RTn * 32; lim = n; }
    else                 { RF = RFB; CF = CFA; rtCount = RTm; ctCount = RTn;
                           sb0 = sbuf + (size_t)S_SLICES * RTn * 32;
                           stride = RTm * 32; lim = m; }

    const int rt = blockIdx.x * 4 + wave;
    if (rt >= rtCount) return;                       // wave-uniform
    float* sby = sb0 + (size_t)blockIdx.y * stride;

    const int ctPer = (ctCount + S_SLICES - 1) / S_SLICES;
    const int ctBeg = min(blockIdx.y * ctPer, ctCount);
    const int ctEnd = min(ctBeg + ctPer, ctCount);

    const bf16x8 afrag = RF[rt * 64 + lane];         // loop-invariant
    const f32x16 zc = {};

    float macc[16];
#pragma unroll
    for (int r = 0; r < 16; ++r) macc[r] = FLT_MAX;

    if (ctBeg < ctEnd) {
        int ct = ctBeg;
        const int last = ctEnd - 1;
        // 4-deep prefetch queue (clamped in prologue; duplicates are
        // min-idempotent)
        bf16x8 q0 = CF[(size_t)ct * 64 + lane];
        bf16x8 q1 = CF[(size_t)min(ct + 1, last) * 64 + lane];
        bf16x8 q2 = CF[(size_t)min(ct + 2, last) * 64 + lane];
        bf16x8 q3 = CF[(size_t)min(ct + 3, last) * 64 + lane];
        f32x16 C0 = __builtin_amdgcn_mfma_f32_32x32x16_bf16(afrag, q0, zc, 0, 0, 0);
        f32x16 C1 = __builtin_amdgcn_mfma_f32_32x32x16_bf16(afrag, q1, zc, 0, 0, 0);

        // steady state: 4 tiles/iter; loads stay >= 2 tiles ahead of their MFMA
        for (; ct + 7 < ctEnd; ct += 4) {
            q0 = CF[(size_t)(ct + 4) * 64 + lane];
            MINC(C0);
            C0 = __builtin_amdgcn_mfma_f32_32x32x16_bf16(afrag, q2, zc, 0, 0, 0);
            q1 = CF[(size_t)(ct + 5) * 64 + lane];
            MINC(C1);
            C1 = __builtin_amdgcn_mfma_f32_32x32x16_bf16(afrag, q3, zc, 0, 0, 0);
            q2 = CF[(size_t)(ct + 6) * 64 + lane];
            MINC(C0);
            C0 = __builtin_amdgcn_mfma_f32_32x32x16_bf16(afrag, q0, zc, 0, 0, 0);
            q3 = CF[(size_t)(ct + 7) * 64 + lane];
            MINC(C1);
            C1 = __builtin_amdgcn_mfma_f32_32x32x16_bf16(afrag, q1, zc, 0, 0, 0);
        }
        // epilogue: C0/C1 hold tiles ct/ct+1 (clamped); q2/q3 hold ct+2/ct+3
        MINC(C0);
        MINC(C1);
        if (ct + 2 < ctEnd) {
            const f32x16 C =
                __builtin_amdgcn_mfma_f32_32x32x16_bf16(afrag, q2, zc, 0, 0, 0);
            MINC(C);
        }
        if (ct + 3 < ctEnd) {
            const f32x16 C =
                __builtin_amdgcn_mfma_f32_32x32x16_bf16(afrag, q3, zc, 0, 0, 0);
            MINC(C);
        }
        for (int t = ct + 4; t < ctEnd; ++t) {
            const bf16x8 b = CF[(size_t)t * 64 + lane];
            const f32x16 C =
                __builtin_amdgcn_mfma_f32_32x32x16_bf16(afrag, b, zc, 0, 0, 0);
            MINC(C);
        }
    }

    // reduce row mins across the 32 cols held in each 32-lane half
#pragma unroll
    for (int r = 0; r < 16; ++r) {
        float v = macc[r];
        v = fminf(v, __shfl_xor(v, 1, 64));
        v = fminf(v, __shfl_xor(v, 2, 64));
        v = fminf(v, __shfl_xor(v, 4, 64));
        v = fminf(v, __shfl_xor(v, 8, 64));
        v = fminf(v, __shfl_xor(v, 16, 64));
        macc[r] = v;
    }
    if ((lane & 31) == 0) {
        const int q4 = (lane >> 5) * 4;              // C map: row=(r&3)+8*(r>>2)+4*q
        float* dst = sby + rt * 32;
#pragma unroll
        for (int r = 0; r < 16; ++r)
            dst[(r & 3) + 8 * (r >> 2) + q4] = macc[r];
    }

    // --- fused finalize: per-rt ticket; 4th slice-wave reduces this rt ---
    unsigned tk = 0u;
    if (lane == 0) {
        __threadfence();                             // publish sby writes (wbl2)
        tk = atomicAdd(&rtc[blockIdx.z * maxRT + rt], 1u);
    }
    tk = __shfl(tk, 0, 64);
    if (tk == S_SLICES - 1) {
        const int idx = rt * 32 + (lane & 31);
        float d = 0.f;
        if (lane < 32) {
            float s = FLT_MAX;
#pragma unroll
            for (int k = 0; k < S_SLICES; ++k)
                s = fminf(s, sb0[(size_t)k * stride + idx]);
            if (idx < lim) {
                d = sqrtf(fmaxf(s, 0.f));
                if (blockIdx.z == 1) out[1 + idx] = d;   // mins_seeds
            }
        }
#pragma unroll
        for (int off = 32; off > 0; off >>= 1)
            d += __shfl_down(d, off, 64);
        if (lane == 0) {
            atomicAdd(&hdr[blockIdx.z], d);
            __threadfence();                         // hdr add before gcnt add
            const unsigned g = atomicAdd((unsigned*)&hdr[2], 1u);
            if (g == (unsigned)(RTn + RTm - 1)) {    // globally last rt group
                const float fa = atomicAdd(&hdr[0], 0.f);
                const float fb = atomicAdd(&hdr[1], 0.f);
                const float loss = fa / (float)n;
                const float loss_seeds = fb / (float)m;
                out[0] = loss + loss_seeds;
                out[1 + m] = loss;
                out[2 + m] = loss_seeds;
            }
        }
    }
}

extern "C" void kernel_launch(void* const* d_in, const int* in_sizes, int n_in,
                              void* d_out, int out_size, void* d_ws, size_t ws_size,
                              hipStream_t stream) {
    const int n = in_sizes[0] / 3;   // true_pos count
    const int m = in_sizes[1] / 3;   // pred_pos count
    const float* A = (const float*)d_in[0];
    const float* B = (const float*)d_in[1];
    float* out = (float*)d_out;

    const int RTn = (n + 31) / 32, RTm = (m + 31) / 32;
    const int maxRT = (RTn > RTm) ? RTn : RTm;
    char* p = (char*)d_ws;
    float*    hdr  = (float*)p;    p += 64;
    unsigned* rtc  = (unsigned*)p; p += (((size_t)2 * maxRT * 4 + 63) / 64) * 64;
    float*    sbuf = (float*)p;    p += (size_t)S_SLICES * (RTn + RTm) * 32 * 4;
    ushort8*  RFA  = (ushort8*)p;  p += (size_t)RTn * 64 * 16;
    ushort8*  CFA  = (ushort8*)p;  p += (size_t)RTn * 64 * 16;
    ushort8*  RFB  = (ushort8*)p;  p += (size_t)RTm * 64 * 16;
    ushort8*  CFB  = (ushort8*)p;

    const int maxPts = maxRT * 32;
    prep_kernel<<<(maxPts + 255) / 256, 256, 0, stream>>>(
        A, B, RFA, CFA, RFB, CFB, hdr, rtc, n, m, RTn, RTm);

    dim3 grid((maxRT + 3) / 4, S_SLICES, 2);
    pairmin_kernel<<<grid, 256, 0, stream>>>(
        (const bf16x8*)RFA, (const bf16x8*)CFA,
        (const bf16x8*)RFB, (const bf16x8*)CFB,
        sbuf, rtc, hdr, out, n, m, RTn, RTm);
}

// Round 2
// 87.498 us; speedup vs baseline: 1.5872x; 1.5872x over previous
//
#include <hip/hip_runtime.h>
#include <cfloat>

typedef __bf16 bf16x8 __attribute__((ext_vector_type(8)));
typedef unsigned short ushort8 __attribute__((ext_vector_type(8)));
typedef float f32x16 __attribute__((ext_vector_type(16)));

// Round 12: 2 row-tiles per wave -> loads/wave halve, compute per load doubles.
// 48 blocks x 8 slices x 2 sides = 768 blocks = 3/CU, fully resident.
#define S_SLICES 8

// fp32 -> bf16 bits, round-to-nearest-even
static __device__ __forceinline__ unsigned short f2bf(float x) {
    unsigned u = __float_as_uint(x);
    return (unsigned short)((u + 0x7FFFu + ((u >> 16) & 1u)) >> 16);
}
static __device__ __forceinline__ float bfbits2f(unsigned short h) {
    return __uint_as_float(((unsigned)h) << 16);
}

// Per point, build TWO 16-element K-vectors (verified round 7/8):
//  row vec: [-2hx,-2hy,-2hz, -2hx,-2hy,-2hz, -2lx,-2ly,-2lz, s1,s2,s3, 1,1,1, 0]
//  col vec: [ hx,  hy,  hz,   lx,  ly,  lz,   hx,  hy,  hz,  1,1,1, t1,t2,t3, 0]
//  => sum_k row[k]*col[k] = nrmRow + nrmCol - 2(hh+hl+lh) ~= d2 (err ~1e-4).
// Fragment storage: frag[tile*64 + q*32 + l5], point = tile*32+l5, k = q*8+j.
// Pad points get nrm=1e30 -> never win a min.
__global__ __launch_bounds__(256) void prep_kernel(
    const float* __restrict__ A, const float* __restrict__ B,
    ushort8* __restrict__ RFA, ushort8* __restrict__ CFA,
    ushort8* __restrict__ RFB, ushort8* __restrict__ CFB,
    float* __restrict__ hdr, int n, int m, int RTn, int RTm)
{
    const int i = blockIdx.x * 256 + threadIdx.x;
    if (i < 8) hdr[i] = 0.f;
    const unsigned short one = 0x3F80;

#pragma unroll
    for (int side = 0; side < 2; ++side) {
        const int cntPts = side ? RTm * 32 : RTn * 32;
        if (i >= cntPts) continue;
        const float* P = side ? B : A;
        const int lim = side ? m : n;
        ushort8* RF = side ? RFB : RFA;
        ushort8* CF = side ? CFB : CFA;

        float x = 0.f, y = 0.f, z = 0.f, nrm = 1e30f;
        if (i < lim) { x = P[3*i]; y = P[3*i+1]; z = P[3*i+2];
                       nrm = fmaf(x, x, fmaf(y, y, z * z)); }
        const unsigned short hx = f2bf(x), hy = f2bf(y), hz = f2bf(z);
        const unsigned short lx = f2bf(x - bfbits2f(hx)),
                             ly = f2bf(y - bfbits2f(hy)),
                             lz = f2bf(z - bfbits2f(hz));
        const unsigned short nhx = f2bf(-2.f * bfbits2f(hx)),
                             nhy = f2bf(-2.f * bfbits2f(hy)),
                             nhz = f2bf(-2.f * bfbits2f(hz));
        const unsigned short nlx = f2bf(-2.f * bfbits2f(lx)),
                             nly = f2bf(-2.f * bfbits2f(ly)),
                             nlz = f2bf(-2.f * bfbits2f(lz));
        float r = nrm;
        const unsigned short s1 = f2bf(r); r -= bfbits2f(s1);
        const unsigned short s2 = f2bf(r); r -= bfbits2f(s2);
        const unsigned short s3 = f2bf(r);

        const int t = i >> 5, l5 = i & 31;
        ushort8 rq0 = { nhx, nhy, nhz, nhx, nhy, nhz, nlx, nly };
        ushort8 rq1 = { nlz, s1, s2, s3, one, one, one, 0 };
        RF[t * 64 + l5]      = rq0;
        RF[t * 64 + 32 + l5] = rq1;
        ushort8 cq0 = { hx, hy, hz, lx, ly, lz, hx, hy };
        ushort8 cq1 = { hz, one, one, one, s1, s2, s3, 0 };
        CF[t * 64 + l5]      = cq0;
        CF[t * 64 + 32 + l5] = cq1;
    }
}

// macc = min(macc, C)   and   macc = min(macc, Ca, Cb) (fuses to v_min3_f32)
#define MINC(M, C)                                          \
    _Pragma("unroll")                                       \
    for (int r = 0; r < 16; ++r) M[r] = fminf(M[r], (C)[r]);
#define MIN3(M, Ca, Cb)                                     \
    _Pragma("unroll")                                       \
    for (int r = 0; r < 16; ++r)                            \
        M[r] = fminf(M[r], fminf((Ca)[r], (Cb)[r]));

// z=0: rows=A vs cols=B -> sbuf side 0 ("mins"); z=1: transposed ("mins_seeds").
// Round 8: generous reg budget keeps C out of scratch. Round 10: keep loads
// >= 1 full iteration ahead of their MFMA. Round 11 FAILED: fusing finalize
// added a per-wave __threadfence (L2 wbl2+inv x768 = +60us storm) -> reverted;
// cross-kernel coherence via launch boundary is free.
// Round 12: each wave owns TWO row-tiles -> per loaded CF tile do 2 MFMAs
// (halves load traffic, doubles latency cover); v_min3 pairing halves min ops.
__global__ __launch_bounds__(256, 3) void pairmin_kernel(
    const bf16x8* __restrict__ RFA, const bf16x8* __restrict__ CFA,
    const bf16x8* __restrict__ RFB, const bf16x8* __restrict__ CFB,
    float* __restrict__ sbuf, int RTn, int RTm)
{
    const int lane = threadIdx.x & 63;
    const int wave = threadIdx.x >> 6;

    const bf16x8* RF; const bf16x8* CF; float* sb; int rtCount, ctCount, stride;
    if (blockIdx.z == 0) { RF = RFA; CF = CFB; rtCount = RTn; ctCount = RTm;
                           sb = sbuf; stride = RTn * 32; }
    else                 { RF = RFB; CF = CFA; rtCount = RTm; ctCount = RTn;
                           sb = sbuf + (size_t)S_SLICES * RTn * 32;
                           stride = RTm * 32; }

    const int pairCount = (rtCount + 1) >> 1;
    const int g = blockIdx.x * 4 + wave;
    if (g >= pairCount) return;                      // wave-uniform
    const int rt0 = g * 2;
    const int rt1 = min(rt0 + 1, rtCount - 1);       // odd tail: dup (benign)
    sb += (size_t)blockIdx.y * stride;

    const int ctPer = (ctCount + S_SLICES - 1) / S_SLICES;
    const int ctBeg = min((int)blockIdx.y * ctPer, ctCount);
    const int ctEnd = min(ctBeg + ctPer, ctCount);

    const bf16x8 a0 = RF[rt0 * 64 + lane];           // loop-invariant
    const bf16x8 a1 = RF[rt1 * 64 + lane];
    const f32x16 zc = {};

    float macc0[16], macc1[16];
#pragma unroll
    for (int r = 0; r < 16; ++r) { macc0[r] = FLT_MAX; macc1[r] = FLT_MAX; }

    if (ctBeg < ctEnd) {
        int ct = ctBeg;
        const int last = ctEnd - 1;
        // 4-deep raw-tile queue (clamped in prologue; duplicates are
        // min-idempotent)
        bf16x8 q0 = CF[(size_t)ct * 64 + lane];
        bf16x8 q1 = CF[(size_t)min(ct + 1, last) * 64 + lane];
        bf16x8 q2 = CF[(size_t)min(ct + 2, last) * 64 + lane];
        bf16x8 q3 = CF[(size_t)min(ct + 3, last) * 64 + lane];
        // C tiles in flight: Cxy = rt_x vs loaded tile y (2 tiles deep)
        f32x16 C00 = __builtin_amdgcn_mfma_f32_32x32x16_bf16(a0, q0, zc, 0, 0, 0);
        f32x16 C10 = __builtin_amdgcn_mfma_f32_32x32x16_bf16(a1, q0, zc, 0, 0, 0);
        f32x16 C01 = __builtin_amdgcn_mfma_f32_32x32x16_bf16(a0, q1, zc, 0, 0, 0);
        f32x16 C11 = __builtin_amdgcn_mfma_f32_32x32x16_bf16(a1, q1, zc, 0, 0, 0);

        // steady state: 4 loaded tiles (8 C tiles) per iter; loads issued
        // >= half an iteration (~110 issue-cycles) before their MFMA.
        // Invariant at top: C** = tiles ct,ct+1; q2,q3 = raw ct+2,ct+3.
        for (; ct + 7 < ctEnd; ct += 4) {
            q0 = CF[(size_t)(ct + 4) * 64 + lane];
            q1 = CF[(size_t)(ct + 5) * 64 + lane];
            MIN3(macc0, C00, C01);
            MIN3(macc1, C10, C11);
            C00 = __builtin_amdgcn_mfma_f32_32x32x16_bf16(a0, q2, zc, 0, 0, 0);
            C10 = __builtin_amdgcn_mfma_f32_32x32x16_bf16(a1, q2, zc, 0, 0, 0);
            C01 = __builtin_amdgcn_mfma_f32_32x32x16_bf16(a0, q3, zc, 0, 0, 0);
            C11 = __builtin_amdgcn_mfma_f32_32x32x16_bf16(a1, q3, zc, 0, 0, 0);
            q2 = CF[(size_t)(ct + 6) * 64 + lane];
            q3 = CF[(size_t)(ct + 7) * 64 + lane];
            MIN3(macc0, C00, C01);
            MIN3(macc1, C10, C11);
            C00 = __builtin_amdgcn_mfma_f32_32x32x16_bf16(a0, q0, zc, 0, 0, 0);
            C10 = __builtin_amdgcn_mfma_f32_32x32x16_bf16(a1, q0, zc, 0, 0, 0);
            C01 = __builtin_amdgcn_mfma_f32_32x32x16_bf16(a0, q1, zc, 0, 0, 0);
            C11 = __builtin_amdgcn_mfma_f32_32x32x16_bf16(a1, q1, zc, 0, 0, 0);
        }
        // tail: C** hold tiles ct,ct+1 (clamped dups idempotent);
        // q2,q3 hold raw ct+2,ct+3
        MIN3(macc0, C00, C01);
        MIN3(macc1, C10, C11);
        if (ct + 2 < ctEnd) {
            const f32x16 c0 =
                __builtin_amdgcn_mfma_f32_32x32x16_bf16(a0, q2, zc, 0, 0, 0);
            const f32x16 c1 =
                __builtin_amdgcn_mfma_f32_32x32x16_bf16(a1, q2, zc, 0, 0, 0);
            MINC(macc0, c0);
            MINC(macc1, c1);
        }
        if (ct + 3 < ctEnd) {
            const f32x16 c0 =
                __builtin_amdgcn_mfma_f32_32x32x16_bf16(a0, q3, zc, 0, 0, 0);
            const f32x16 c1 =
                __builtin_amdgcn_mfma_f32_32x32x16_bf16(a1, q3, zc, 0, 0, 0);
            MINC(macc0, c0);
            MINC(macc1, c1);
        }
        for (int t = ct + 4; t < ctEnd; ++t) {
            const bf16x8 b = CF[(size_t)t * 64 + lane];
            const f32x16 c0 =
                __builtin_amdgcn_mfma_f32_32x32x16_bf16(a0, b, zc, 0, 0, 0);
            const f32x16 c1 =
                __builtin_amdgcn_mfma_f32_32x32x16_bf16(a1, b, zc, 0, 0, 0);
            MINC(macc0, c0);
            MINC(macc1, c1);
        }
    }

    // reduce row mins across the 32 cols held in each 32-lane half
#pragma unroll
    for (int r = 0; r < 16; ++r) {
        float v0 = macc0[r], v1 = macc1[r];
        v0 = fminf(v0, __shfl_xor(v0, 1, 64));
        v1 = fminf(v1, __shfl_xor(v1, 1, 64));
        v0 = fminf(v0, __shfl_xor(v0, 2, 64));
        v1 = fminf(v1, __shfl_xor(v1, 2, 64));
        v0 = fminf(v0, __shfl_xor(v0, 4, 64));
        v1 = fminf(v1, __shfl_xor(v1, 4, 64));
        v0 = fminf(v0, __shfl_xor(v0, 8, 64));
        v1 = fminf(v1, __shfl_xor(v1, 8, 64));
        v0 = fminf(v0, __shfl_xor(v0, 16, 64));
        v1 = fminf(v1, __shfl_xor(v1, 16, 64));
        macc0[r] = v0;
        macc1[r] = v1;
    }
    if ((lane & 31) == 0) {
        const int q4 = (lane >> 5) * 4;              // C map: row=(r&3)+8*(r>>2)+4*q
        float* dst0 = sb + rt0 * 32;
        float* dst1 = sb + rt1 * 32;
#pragma unroll
        for (int r = 0; r < 16; ++r) {
            dst0[(r & 3) + 8 * (r >> 2) + q4] = macc0[r];
            dst1[(r & 3) + 8 * (r >> 2) + q4] = macc1[r];
        }
    }
}

// out layout: [loss+loss_seeds, mins_seeds(m), loss, loss_seeds]
__global__ __launch_bounds__(256) void finalize_kernel(
    const float* __restrict__ sbuf, float* __restrict__ hdr,
    float* __restrict__ out, int n, int m, int RTn, int RTm)
{
    const int i = blockIdx.x * 256 + threadIdx.x;
    const int strideA = RTn * 32, strideB = RTm * 32;
    const float* sbB = sbuf + (size_t)S_SLICES * strideA;

    float sa = 0.f, sb_ = 0.f;
    if (i < n) {
        float s = FLT_MAX;
#pragma unroll
        for (int k = 0; k < S_SLICES; ++k) s = fminf(s, sbuf[(size_t)k * strideA + i]);
        sa = sqrtf(fmaxf(s, 0.f));
    }
    if (i < m) {
        float s = FLT_MAX;
#pragma unroll
        for (int k = 0; k < S_SLICES; ++k) s = fminf(s, sbB[(size_t)k * strideB + i]);
        const float v = sqrtf(fmaxf(s, 0.f));
        out[1 + i] = v;                  // mins_seeds
        sb_ = v;
    }

#pragma unroll
    for (int off = 32; off > 0; off >>= 1) {
        sa  += __shfl_down(sa,  off, 64);
        sb_ += __shfl_down(sb_, off, 64);
    }
    __shared__ float reda[4], redb[4];
    const int wave = threadIdx.x >> 6;
    const int lane = threadIdx.x & 63;
    if (lane == 0) { reda[wave] = sa; redb[wave] = sb_; }
    __syncthreads();

    if (threadIdx.x == 0) {
        const float ta = reda[0] + reda[1] + reda[2] + reda[3];
        const float tb = redb[0] + redb[1] + redb[2] + redb[3];
        atomicAdd(&hdr[0], ta);
        atomicAdd(&hdr[1], tb);
        __threadfence();
        const unsigned ticket = atomicAdd((unsigned*)&hdr[2], 1u);
        if (ticket == (unsigned)(gridDim.x - 1)) {
            const float fa = atomicAdd(&hdr[0], 0.f);
            const float fb = atomicAdd(&hdr[1], 0.f);
            const float loss = fa / (float)n;
            const float loss_seeds = fb / (float)m;
            out[0] = loss + loss_seeds;
            out[1 + m] = loss;
            out[2 + m] = loss_seeds;
        }
    }
}

extern "C" void kernel_launch(void* const* d_in, const int* in_sizes, int n_in,
                              void* d_out, int out_size, void* d_ws, size_t ws_size,
                              hipStream_t stream) {
    const int n = in_sizes[0] / 3;   // true_pos count
    const int m = in_sizes[1] / 3;   // pred_pos count
    const float* A = (const float*)d_in[0];
    const float* B = (const float*)d_in[1];
    float* out = (float*)d_out;

    const int RTn = (n + 31) / 32, RTm = (m + 31) / 32;
    char* p = (char*)d_ws;
    float*   hdr  = (float*)p;    p += 64;
    float*   sbuf = (float*)p;    p += (size_t)S_SLICES * (RTn + RTm) * 32 * 4;
    ushort8* RFA  = (ushort8*)p;  p += (size_t)RTn * 64 * 16;
    ushort8* CFA  = (ushort8*)p;  p += (size_t)RTn * 64 * 16;
    ushort8* RFB  = (ushort8*)p;  p += (size_t)RTm * 64 * 16;
    ushort8* CFB  = (ushort8*)p;

    const int maxRT = (RTn > RTm) ? RTn : RTm;
    const int maxPts = maxRT * 32;
    prep_kernel<<<(maxPts + 255) / 256, 256, 0, stream>>>(
        A, B, RFA, CFA, RFB, CFB, hdr, n, m, RTn, RTm);

    const int maxPair = (maxRT + 1) >> 1;
    dim3 grid((maxPair + 3) / 4, S_SLICES, 2);
    pairmin_kernel<<<grid, 256, 0, stream>>>(
        (const bf16x8*)RFA, (const bf16x8*)CFA,
        (const bf16x8*)RFB, (const bf16x8*)CFB, sbuf, RTn, RTm);

    const int maxnm = (n > m) ? n : m;
    finalize_kernel<<<(maxnm + 255) / 256, 256, 0, stream>>>(
        sbuf, hdr, out, n, m, RTn, RTm);
}

// Round 3
// 86.553 us; speedup vs baseline: 1.6046x; 1.0109x over previous
//
#include <hip/hip_runtime.h>
#include <cfloat>

typedef __bf16 bf16x8 __attribute__((ext_vector_type(8)));
typedef unsigned short ushort8 __attribute__((ext_vector_type(8)));
typedef float f32x16 __attribute__((ext_vector_type(16)));

#define S_SLICES 4   // 96 x 4 x 2 = 768 blocks = 3/CU, fully resident
#define CHUNK_T 48   // col-tiles staged per LDS chunk (48 KB; 3 blocks/CU -> 144/160 KB)

// fp32 -> bf16 bits, round-to-nearest-even
static __device__ __forceinline__ unsigned short f2bf(float x) {
    unsigned u = __float_as_uint(x);
    return (unsigned short)((u + 0x7FFFu + ((u >> 16) & 1u)) >> 16);
}
static __device__ __forceinline__ float bfbits2f(unsigned short h) {
    return __uint_as_float(((unsigned)h) << 16);
}

// Per point, build TWO 16-element K-vectors (verified round 7/8):
//  row vec: [-2hx,-2hy,-2hz, -2hx,-2hy,-2hz, -2lx,-2ly,-2lz, s1,s2,s3, 1,1,1, 0]
//  col vec: [ hx,  hy,  hz,   lx,  ly,  lz,   hx,  hy,  hz,  1,1,1, t1,t2,t3, 0]
//  => sum_k row[k]*col[k] = nrmRow + nrmCol - 2(hh+hl+lh) ~= d2 (err ~1e-4).
// Fragment storage: frag[tile*64 + q*32 + l5], point = tile*32+l5, k = q*8+j.
// Pad points get nrm=1e30 -> never win a min.
__global__ __launch_bounds__(256) void prep_kernel(
    const float* __restrict__ A, const float* __restrict__ B,
    ushort8* __restrict__ RFA, ushort8* __restrict__ CFA,
    ushort8* __restrict__ RFB, ushort8* __restrict__ CFB,
    float* __restrict__ hdr, int n, int m, int RTn, int RTm)
{
    const int i = blockIdx.x * 256 + threadIdx.x;
    if (i < 8) hdr[i] = 0.f;
    const unsigned short one = 0x3F80;

#pragma unroll
    for (int side = 0; side < 2; ++side) {
        const int cntPts = side ? RTm * 32 : RTn * 32;
        if (i >= cntPts) continue;
        const float* P = side ? B : A;
        const int lim = side ? m : n;
        ushort8* RF = side ? RFB : RFA;
        ushort8* CF = side ? CFB : CFA;

        float x = 0.f, y = 0.f, z = 0.f, nrm = 1e30f;
        if (i < lim) { x = P[3*i]; y = P[3*i+1]; z = P[3*i+2];
                       nrm = fmaf(x, x, fmaf(y, y, z * z)); }
        const unsigned short hx = f2bf(x), hy = f2bf(y), hz = f2bf(z);
        const unsigned short lx = f2bf(x - bfbits2f(hx)),
                             ly = f2bf(y - bfbits2f(hy)),
                             lz = f2bf(z - bfbits2f(hz));
        const unsigned short nhx = f2bf(-2.f * bfbits2f(hx)),
                             nhy = f2bf(-2.f * bfbits2f(hy)),
                             nhz = f2bf(-2.f * bfbits2f(hz));
        const unsigned short nlx = f2bf(-2.f * bfbits2f(lx)),
                             nly = f2bf(-2.f * bfbits2f(ly)),
                             nlz = f2bf(-2.f * bfbits2f(lz));
        float r = nrm;
        const unsigned short s1 = f2bf(r); r -= bfbits2f(s1);
        const unsigned short s2 = f2bf(r); r -= bfbits2f(s2);
        const unsigned short s3 = f2bf(r);

        const int t = i >> 5, l5 = i & 31;
        ushort8 rq0 = { nhx, nhy, nhz, nhx, nhy, nhz, nlx, nly };
        ushort8 rq1 = { nlz, s1, s2, s3, one, one, one, 0 };
        RF[t * 64 + l5]      = rq0;
        RF[t * 64 + 32 + l5] = rq1;
        ushort8 cq0 = { hx, hy, hz, lx, ly, lz, hx, hy };
        ushort8 cq1 = { hz, one, one, one, s1, s2, s3, 0 };
        CF[t * 64 + l5]      = cq0;
        CF[t * 64 + 32 + l5] = cq1;
    }
}

// macc = min(macc, C); and paired retire (fuses to v_min3_f32)
#define MINC(C)                                             \
    _Pragma("unroll")                                       \
    for (int r = 0; r < 16; ++r) macc[r] = fminf(macc[r], (C)[r]);
#define MIN3(Ca, Cb)                                        \
    _Pragma("unroll")                                       \
    for (int r = 0; r < 16; ++r)                            \
        macc[r] = fminf(macc[r], fminf((Ca)[r], (Cb)[r]));

// z=0: rows=A vs cols=B -> sbuf side 0 ("mins"); z=1: transposed ("mins_seeds").
// Round 8: generous reg budget keeps C in VGPRs. Round 10: 4-deep prefetch.
// Round 11 FAILED: per-wave __threadfence = L2 wbl2+inv storm -> never fuse
// finalize; launch-boundary coherence is free. Round 12 FAILED: rt-pair +
// (256,3) + S_SLICES=8 regressed pairmin ~24->~33us (doubled per-wave state).
// Round 13 theory: pairmin is vmem-latency-bound (96 independent L2/L3-latency
// loads/wave, 4-tile lookahead, 3 waves/SIMD; 4 waves pull the same CF stream
// redundantly). Fix: stage the block-shared ct slice into LDS once per block
// via global_load_lds (width 16), read tiles via ds_read_b128 (~120cy, covered
// by the 4-deep pipeline); pair C0/C1 retires into v_min3 (halves min ops).
__global__ __launch_bounds__(256, 3) void pairmin_kernel(
    const bf16x8* __restrict__ RFA, const bf16x8* __restrict__ CFA,
    const bf16x8* __restrict__ RFB, const bf16x8* __restrict__ CFB,
    float* __restrict__ sbuf, int RTn, int RTm)
{
    const int lane = threadIdx.x & 63;
    const int wave = threadIdx.x >> 6;

    const bf16x8* RF; const bf16x8* CF; float* sb; int rtCount, ctCount, stride;
    if (blockIdx.z == 0) { RF = RFA; CF = CFB; rtCount = RTn; ctCount = RTm;
                           sb = sbuf; stride = RTn * 32; }
    else                 { RF = RFB; CF = CFA; rtCount = RTm; ctCount = RTn;
                           sb = sbuf + (size_t)S_SLICES * RTn * 32;
                           stride = RTm * 32; }

    const int rt = blockIdx.x * 4 + wave;
    const bool live = rt < rtCount;                  // dead waves still stage+barrier
    const int rtc = live ? rt : rtCount - 1;
    sb += (size_t)blockIdx.y * stride;

    const int ctPer = (ctCount + S_SLICES - 1) / S_SLICES;
    const int ctBeg = min((int)blockIdx.y * ctPer, ctCount);
    const int ctEnd = min(ctBeg + ctPer, ctCount);

    const bf16x8 afrag = RF[rtc * 64 + lane];        // loop-invariant
    const f32x16 zc = {};

    float macc[16];
#pragma unroll
    for (int r = 0; r < 16; ++r) macc[r] = FLT_MAX;

    __shared__ __align__(16) char ldsbuf[CHUNK_T * 1024];
    const bf16x8* L = (const bf16x8*)ldsbuf;
    const char* CFb = (const char*)CF;

    for (int cb = ctBeg; cb < ctEnd; cb += CHUNK_T) {
        const int T = min(CHUNK_T, ctEnd - cb);
        const int Tbytes = T << 10;

        __syncthreads();                             // prev chunk's reads done
        // stage T KB: round r covers 4 KB; wave w handles [r*4096 + w*1024 + lane*16]
        const size_t gb = ((size_t)cb) << 10;
        const int nr = (Tbytes + 4095) >> 12;
        for (int r = 0; r < nr; ++r) {
            const int off = (r << 12) + (wave << 10) + (lane << 4);
            if (off < Tbytes)
                __builtin_amdgcn_global_load_lds(
                    (const __attribute__((address_space(1))) void*)(CFb + gb + off),
                    (__attribute__((address_space(3))) void*)(ldsbuf + (r << 12) + (wave << 10)),
                    16, 0, 0);
        }
        __syncthreads();                             // drains vmcnt; data visible

        int t0 = 0;
        if (T >= 4) {
            bf16x8 q0 = L[0 * 64 + lane];
            bf16x8 q1 = L[1 * 64 + lane];
            bf16x8 q2 = L[2 * 64 + lane];
            bf16x8 q3 = L[3 * 64 + lane];
            f32x16 C0 = __builtin_amdgcn_mfma_f32_32x32x16_bf16(afrag, q0, zc, 0, 0, 0);
            f32x16 C1 = __builtin_amdgcn_mfma_f32_32x32x16_bf16(afrag, q1, zc, 0, 0, 0);

            // invariant at loop top: C0,C1 = tiles t,t+1; q2,q3 = tiles t+2,t+3
            int t = 0;
            for (; t + 7 < T; t += 4) {
                q0 = L[(t + 4) * 64 + lane];
                q1 = L[(t + 5) * 64 + lane];
                MIN3(C0, C1);                        // retire t, t+1
                C0 = __builtin_amdgcn_mfma_f32_32x32x16_bf16(afrag, q2, zc, 0, 0, 0);
                C1 = __builtin_amdgcn_mfma_f32_32x32x16_bf16(afrag, q3, zc, 0, 0, 0);
                q2 = L[(t + 6) * 64 + lane];
                q3 = L[(t + 7) * 64 + lane];
                MIN3(C0, C1);                        // retire t+2, t+3
                C0 = __builtin_amdgcn_mfma_f32_32x32x16_bf16(afrag, q0, zc, 0, 0, 0);
                C1 = __builtin_amdgcn_mfma_f32_32x32x16_bf16(afrag, q1, zc, 0, 0, 0);
            }
            // exit invariant: tiles t..t+3 valid (t <= T-4 always holds here)
            MIN3(C0, C1);
            C0 = __builtin_amdgcn_mfma_f32_32x32x16_bf16(afrag, q2, zc, 0, 0, 0);
            C1 = __builtin_amdgcn_mfma_f32_32x32x16_bf16(afrag, q3, zc, 0, 0, 0);
            MIN3(C0, C1);
            t0 = t + 4;
        }
        for (int u = t0; u < T; ++u) {               // T<4 path / stragglers
            const bf16x8 b = L[u * 64 + lane];
            const f32x16 C =
                __builtin_amdgcn_mfma_f32_32x32x16_bf16(afrag, b, zc, 0, 0, 0);
            MINC(C);
        }
    }

    // reduce row mins across the 32 cols held in each 32-lane half
#pragma unroll
    for (int r = 0; r < 16; ++r) {
        float v = macc[r];
        v = fminf(v, __shfl_xor(v, 1, 64));
        v = fminf(v, __shfl_xor(v, 2, 64));
        v = fminf(v, __shfl_xor(v, 4, 64));
        v = fminf(v, __shfl_xor(v, 8, 64));
        v = fminf(v, __shfl_xor(v, 16, 64));
        macc[r] = v;
    }
    if (live && (lane & 31) == 0) {
        const int q4 = (lane >> 5) * 4;              // C map: row=(r&3)+8*(r>>2)+4*q
        float* dst = sb + rt * 32;
#pragma unroll
        for (int r = 0; r < 16; ++r)
            dst[(r & 3) + 8 * (r >> 2) + q4] = macc[r];
    }
}

// out layout: [loss+loss_seeds, mins_seeds(m), loss, loss_seeds]
__global__ __launch_bounds__(256) void finalize_kernel(
    const float* __restrict__ sbuf, float* __restrict__ hdr,
    float* __restrict__ out, int n, int m, int RTn, int RTm)
{
    const int i = blockIdx.x * 256 + threadIdx.x;
    const int strideA = RTn * 32, strideB = RTm * 32;
    const float* sbB = sbuf + (size_t)S_SLICES * strideA;

    float sa = 0.f, sb_ = 0.f;
    if (i < n) {
        float s = FLT_MAX;
#pragma unroll
        for (int k = 0; k < S_SLICES; ++k) s = fminf(s, sbuf[(size_t)k * strideA + i]);
        sa = sqrtf(fmaxf(s, 0.f));
    }
    if (i < m) {
        float s = FLT_MAX;
#pragma unroll
        for (int k = 0; k < S_SLICES; ++k) s = fminf(s, sbB[(size_t)k * strideB + i]);
        const float v = sqrtf(fmaxf(s, 0.f));
        out[1 + i] = v;                  // mins_seeds
        sb_ = v;
    }

#pragma unroll
    for (int off = 32; off > 0; off >>= 1) {
        sa  += __shfl_down(sa,  off, 64);
        sb_ += __shfl_down(sb_, off, 64);
    }
    __shared__ float reda[4], redb[4];
    const int wave = threadIdx.x >> 6;
    const int lane = threadIdx.x & 63;
    if (lane == 0) { reda[wave] = sa; redb[wave] = sb_; }
    __syncthreads();

    if (threadIdx.x == 0) {
        const float ta = reda[0] + reda[1] + reda[2] + reda[3];
        const float tb = redb[0] + redb[1] + redb[2] + redb[3];
        atomicAdd(&hdr[0], ta);
        atomicAdd(&hdr[1], tb);
        __threadfence();
        const unsigned ticket = atomicAdd((unsigned*)&hdr[2], 1u);
        if (ticket == (unsigned)(gridDim.x - 1)) {
            const float fa = atomicAdd(&hdr[0], 0.f);
            const float fb = atomicAdd(&hdr[1], 0.f);
            const float loss = fa / (float)n;
            const float loss_seeds = fb / (float)m;
            out[0] = loss + loss_seeds;
            out[1 + m] = loss;
            out[2 + m] = loss_seeds;
        }
    }
}

extern "C" void kernel_launch(void* const* d_in, const int* in_sizes, int n_in,
                              void* d_out, int out_size, void* d_ws, size_t ws_size,
                              hipStream_t stream) {
    const int n = in_sizes[0] / 3;   // true_pos count
    const int m = in_sizes[1] / 3;   // pred_pos count
    const float* A = (const float*)d_in[0];
    const float* B = (const float*)d_in[1];
    float* out = (float*)d_out;

    const int RTn = (n + 31) / 32, RTm = (m + 31) / 32;
    char* p = (char*)d_ws;
    float*   hdr  = (float*)p;    p += 64;
    float*   sbuf = (float*)p;    p += (size_t)S_SLICES * (RTn + RTm) * 32 * 4;
    ushort8* RFA  = (ushort8*)p;  p += (size_t)RTn * 64 * 16;
    ushort8* CFA  = (ushort8*)p;  p += (size_t)RTn * 64 * 16;
    ushort8* RFB  = (ushort8*)p;  p += (size_t)RTm * 64 * 16;
    ushort8* CFB  = (ushort8*)p;

    const int maxRT = (RTn > RTm) ? RTn : RTm;
    const int maxPts = maxRT * 32;
    prep_kernel<<<(maxPts + 255) / 256, 256, 0, stream>>>(
        A, B, RFA, CFA, RFB, CFB, hdr, n, m, RTn, RTm);

    dim3 grid((maxRT + 3) / 4, S_SLICES, 2);
    pairmin_kernel<<<grid, 256, 0, stream>>>(
        (const bf16x8*)RFA, (const bf16x8*)CFA,
        (const bf16x8*)RFB, (const bf16x8*)CFB, sbuf, RTn, RTm);

    const int maxnm = (n > m) ? n : m;
    finalize_kernel<<<(maxnm + 255) / 256, 256, 0, stream>>>(
        sbuf, hdr, out, n, m, RTn, RTm);
}

// Round 4
// 85.210 us; speedup vs baseline: 1.6299x; 1.0158x over previous
//
#include <hip/hip_runtime.h>
#include <cfloat>

typedef __bf16 bf16x8 __attribute__((ext_vector_type(8)));
typedef unsigned short ushort8 __attribute__((ext_vector_type(8)));
typedef float f32x16 __attribute__((ext_vector_type(16)));

#define S_SLICES 4   // 96 x 4 x 2 = 768 blocks = 3/CU, fully resident

// fp32 -> bf16 bits, round-to-nearest-even
static __device__ __forceinline__ unsigned short f2bf(float x) {
    unsigned u = __float_as_uint(x);
    return (unsigned short)((u + 0x7FFFu + ((u >> 16) & 1u)) >> 16);
}
static __device__ __forceinline__ float bfbits2f(unsigned short h) {
    return __uint_as_float(((unsigned)h) << 16);
}

// Per point, build TWO 16-element K-vectors (verified round 7/8):
//  row vec: [-2hx,-2hy,-2hz, -2hx,-2hy,-2hz, -2lx,-2ly,-2lz, s1,s2,s3, 1,1,1, 0]
//  col vec: [ hx,  hy,  hz,   lx,  ly,  lz,   hx,  hy,  hz,  1,1,1, t1,t2,t3, 0]
//  => sum_k row[k]*col[k] = nrmRow + nrmCol - 2(hh+hl+lh) ~= d2 (err ~1e-4).
// Fragment storage: frag[tile*64 + q*32 + l5], point = tile*32+l5, k = q*8+j.
// Pad points get nrm=1e30 -> never win a min.
__global__ __launch_bounds__(256) void prep_kernel(
    const float* __restrict__ A, const float* __restrict__ B,
    ushort8* __restrict__ RFA, ushort8* __restrict__ CFA,
    ushort8* __restrict__ RFB, ushort8* __restrict__ CFB,
    float* __restrict__ hdr, int n, int m, int RTn, int RTm)
{
    const int i = blockIdx.x * 256 + threadIdx.x;
    if (i < 8) hdr[i] = 0.f;
    const unsigned short one = 0x3F80;

#pragma unroll
    for (int side = 0; side < 2; ++side) {
        const int cntPts = side ? RTm * 32 : RTn * 32;
        if (i >= cntPts) continue;
        const float* P = side ? B : A;
        const int lim = side ? m : n;
        ushort8* RF = side ? RFB : RFA;
        ushort8* CF = side ? CFB : CFA;

        float x = 0.f, y = 0.f, z = 0.f, nrm = 1e30f;
        if (i < lim) { x = P[3*i]; y = P[3*i+1]; z = P[3*i+2];
                       nrm = fmaf(x, x, fmaf(y, y, z * z)); }
        const unsigned short hx = f2bf(x), hy = f2bf(y), hz = f2bf(z);
        const unsigned short lx = f2bf(x - bfbits2f(hx)),
                             ly = f2bf(y - bfbits2f(hy)),
                             lz = f2bf(z - bfbits2f(hz));
        const unsigned short nhx = f2bf(-2.f * bfbits2f(hx)),
                             nhy = f2bf(-2.f * bfbits2f(hy)),
                             nhz = f2bf(-2.f * bfbits2f(hz));
        const unsigned short nlx = f2bf(-2.f * bfbits2f(lx)),
                             nly = f2bf(-2.f * bfbits2f(ly)),
                             nlz = f2bf(-2.f * bfbits2f(lz));
        float r = nrm;
        const unsigned short s1 = f2bf(r); r -= bfbits2f(s1);
        const unsigned short s2 = f2bf(r); r -= bfbits2f(s2);
        const unsigned short s3 = f2bf(r);

        const int t = i >> 5, l5 = i & 31;
        ushort8 rq0 = { nhx, nhy, nhz, nhx, nhy, nhz, nlx, nly };
        ushort8 rq1 = { nlz, s1, s2, s3, one, one, one, 0 };
        RF[t * 64 + l5]      = rq0;
        RF[t * 64 + 32 + l5] = rq1;
        ushort8 cq0 = { hx, hy, hz, lx, ly, lz, hx, hy };
        ushort8 cq1 = { hz, one, one, one, s1, s2, s3, 0 };
        CF[t * 64 + l5]      = cq0;
        CF[t * 64 + 32 + l5] = cq1;
    }
}

// macc = min(macc, C); and paired retire (fuses to v_min3_f32)
#define MINC(C)                                             \
    _Pragma("unroll")                                       \
    for (int r = 0; r < 16; ++r) macc[r] = fminf(macc[r], (C)[r]);
#define MIN3(Ca, Cb)                                        \
    _Pragma("unroll")                                       \
    for (int r = 0; r < 16; ++r)                            \
        macc[r] = fminf(macc[r], fminf((Ca)[r], (Cb)[r]));

// z=0: rows=A vs cols=B -> sbuf side 0 ("mins"); z=1: transposed ("mins_seeds").
// History: R8: (256,4) keeps C in VGPRs. R10: prefetch queue. R11 FAILED:
// per-wave __threadfence = L2 wbl2+inv storm. R12 FAILED: rt-pair + (256,3)
// + S_SLICES=8 (+9us). R13 FAILED: LDS staging + (256,3) (+8us; in-phase
// vmcnt(0) drains, ds_read no cheaper than L1 vmem). Lesson: R0 streaming
// structure + (256,4) is the proven base; change ONE variable.
// R14: queue 4->8 deep (loads ~6-8 tiles ahead ~ 150-200 issue-cyc x3 waves
// ~ 500+ cyc cover vs post-poison L3-class latency) + v_min3 retire pairing.
__global__ __launch_bounds__(256, 4) void pairmin_kernel(
    const bf16x8* __restrict__ RFA, const bf16x8* __restrict__ CFA,
    const bf16x8* __restrict__ RFB, const bf16x8* __restrict__ CFB,
    float* __restrict__ sbuf, int RTn, int RTm)
{
    const int lane = threadIdx.x & 63;
    const int wave = threadIdx.x >> 6;

    const bf16x8* RF; const bf16x8* CF; float* sb; int rtCount, ctCount, stride;
    if (blockIdx.z == 0) { RF = RFA; CF = CFB; rtCount = RTn; ctCount = RTm;
                           sb = sbuf; stride = RTn * 32; }
    else                 { RF = RFB; CF = CFA; rtCount = RTm; ctCount = RTn;
                           sb = sbuf + (size_t)S_SLICES * RTn * 32;
                           stride = RTm * 32; }

    const int rt = blockIdx.x * 4 + wave;
    if (rt >= rtCount) return;                       // wave-uniform
    sb += (size_t)blockIdx.y * stride;

    const int ctPer = (ctCount + S_SLICES - 1) / S_SLICES;
    const int ctBeg = min((int)blockIdx.y * ctPer, ctCount);
    const int ctEnd = min(ctBeg + ctPer, ctCount);
    const int T = ctEnd - ctBeg;

    const bf16x8 afrag = RF[rt * 64 + lane];         // loop-invariant
    const bf16x8* P = CF + (size_t)ctBeg * 64;       // tile t at P[t*64 + lane]
    const f32x16 zc = {};

    float macc[16];
#pragma unroll
    for (int r = 0; r < 16; ++r) macc[r] = FLT_MAX;

    if (T >= 8) {
        // 8-deep prefetch queue; 2 C tiles in flight.
        bf16x8 q0 = P[0 * 64 + lane];
        bf16x8 q1 = P[1 * 64 + lane];
        bf16x8 q2 = P[2 * 64 + lane];
        bf16x8 q3 = P[3 * 64 + lane];
        bf16x8 q4 = P[4 * 64 + lane];
        bf16x8 q5 = P[5 * 64 + lane];
        bf16x8 q6 = P[6 * 64 + lane];
        bf16x8 q7 = P[7 * 64 + lane];
        f32x16 C0 = __builtin_amdgcn_mfma_f32_32x32x16_bf16(afrag, q0, zc, 0, 0, 0);
        f32x16 C1 = __builtin_amdgcn_mfma_f32_32x32x16_bf16(afrag, q1, zc, 0, 0, 0);

        // invariant at loop top: C0,C1 = tiles t,t+1; q2..q7 = tiles t+2..t+7
        int t = 0;
        for (; t + 15 < T; t += 8) {
            q0 = P[(size_t)(t + 8) * 64 + lane];
            q1 = P[(size_t)(t + 9) * 64 + lane];
            MIN3(C0, C1);                            // retire t, t+1
            C0 = __builtin_amdgcn_mfma_f32_32x32x16_bf16(afrag, q2, zc, 0, 0, 0);
            C1 = __builtin_amdgcn_mfma_f32_32x32x16_bf16(afrag, q3, zc, 0, 0, 0);
            q2 = P[(size_t)(t + 10) * 64 + lane];
            q3 = P[(size_t)(t + 11) * 64 + lane];
            MIN3(C0, C1);                            // retire t+2, t+3
            C0 = __builtin_amdgcn_mfma_f32_32x32x16_bf16(afrag, q4, zc, 0, 0, 0);
            C1 = __builtin_amdgcn_mfma_f32_32x32x16_bf16(afrag, q5, zc, 0, 0, 0);
            q4 = P[(size_t)(t + 12) * 64 + lane];
            q5 = P[(size_t)(t + 13) * 64 + lane];
            MIN3(C0, C1);                            // retire t+4, t+5
            C0 = __builtin_amdgcn_mfma_f32_32x32x16_bf16(afrag, q6, zc, 0, 0, 0);
            C1 = __builtin_amdgcn_mfma_f32_32x32x16_bf16(afrag, q7, zc, 0, 0, 0);
            q6 = P[(size_t)(t + 14) * 64 + lane];
            q7 = P[(size_t)(t + 15) * 64 + lane];
            MIN3(C0, C1);                            // retire t+6, t+7
            C0 = __builtin_amdgcn_mfma_f32_32x32x16_bf16(afrag, q0, zc, 0, 0, 0);
            C1 = __builtin_amdgcn_mfma_f32_32x32x16_bf16(afrag, q1, zc, 0, 0, 0);
        }
        // tiles t..t+7 live in C0,C1 (t,t+1) and q2..q7
        MIN3(C0, C1);
        C0 = __builtin_amdgcn_mfma_f32_32x32x16_bf16(afrag, q2, zc, 0, 0, 0);
        C1 = __builtin_amdgcn_mfma_f32_32x32x16_bf16(afrag, q3, zc, 0, 0, 0);
        MIN3(C0, C1);
        C0 = __builtin_amdgcn_mfma_f32_32x32x16_bf16(afrag, q4, zc, 0, 0, 0);
        C1 = __builtin_amdgcn_mfma_f32_32x32x16_bf16(afrag, q5, zc, 0, 0, 0);
        MIN3(C0, C1);
        C0 = __builtin_amdgcn_mfma_f32_32x32x16_bf16(afrag, q6, zc, 0, 0, 0);
        C1 = __builtin_amdgcn_mfma_f32_32x32x16_bf16(afrag, q7, zc, 0, 0, 0);
        MIN3(C0, C1);
        for (int u = t + 8; u < T; ++u) {            // stragglers (T % 8 != 0)
            const bf16x8 b = P[(size_t)u * 64 + lane];
            const f32x16 C =
                __builtin_amdgcn_mfma_f32_32x32x16_bf16(afrag, b, zc, 0, 0, 0);
            MINC(C);
        }
    } else {
        for (int u = 0; u < T; ++u) {
            const bf16x8 b = P[(size_t)u * 64 + lane];
            const f32x16 C =
                __builtin_amdgcn_mfma_f32_32x32x16_bf16(afrag, b, zc, 0, 0, 0);
            MINC(C);
        }
    }

    // reduce row mins across the 32 cols held in each 32-lane half
#pragma unroll
    for (int r = 0; r < 16; ++r) {
        float v = macc[r];
        v = fminf(v, __shfl_xor(v, 1, 64));
        v = fminf(v, __shfl_xor(v, 2, 64));
        v = fminf(v, __shfl_xor(v, 4, 64));
        v = fminf(v, __shfl_xor(v, 8, 64));
        v = fminf(v, __shfl_xor(v, 16, 64));
        macc[r] = v;
    }
    if ((lane & 31) == 0) {
        const int q4 = (lane >> 5) * 4;              // C map: row=(r&3)+8*(r>>2)+4*q
        float* dst = sb + rt * 32;
#pragma unroll
        for (int r = 0; r < 16; ++r)
            dst[(r & 3) + 8 * (r >> 2) + q4] = macc[r];
    }
}

// out layout: [loss+loss_seeds, mins_seeds(m), loss, loss_seeds]
__global__ __launch_bounds__(256) void finalize_kernel(
    const float* __restrict__ sbuf, float* __restrict__ hdr,
    float* __restrict__ out, int n, int m, int RTn, int RTm)
{
    const int i = blockIdx.x * 256 + threadIdx.x;
    const int strideA = RTn * 32, strideB = RTm * 32;
    const float* sbB = sbuf + (size_t)S_SLICES * strideA;

    float sa = 0.f, sb_ = 0.f;
    if (i < n) {
        float s = FLT_MAX;
#pragma unroll
        for (int k = 0; k < S_SLICES; ++k) s = fminf(s, sbuf[(size_t)k * strideA + i]);
        sa = sqrtf(fmaxf(s, 0.f));
    }
    if (i < m) {
        float s = FLT_MAX;
#pragma unroll
        for (int k = 0; k < S_SLICES; ++k) s = fminf(s, sbB[(size_t)k * strideB + i]);
        const float v = sqrtf(fmaxf(s, 0.f));
        out[1 + i] = v;                  // mins_seeds
        sb_ = v;
    }

#pragma unroll
    for (int off = 32; off > 0; off >>= 1) {
        sa  += __shfl_down(sa,  off, 64);
        sb_ += __shfl_down(sb_, off, 64);
    }
    __shared__ float reda[4], redb[4];
    const int wave = threadIdx.x >> 6;
    const int lane = threadIdx.x & 63;
    if (lane == 0) { reda[wave] = sa; redb[wave] = sb_; }
    __syncthreads();

    if (threadIdx.x == 0) {
        const float ta = reda[0] + reda[1] + reda[2] + reda[3];
        const float tb = redb[0] + redb[1] + redb[2] + redb[3];
        atomicAdd(&hdr[0], ta);
        atomicAdd(&hdr[1], tb);
        __threadfence();
        const unsigned ticket = atomicAdd((unsigned*)&hdr[2], 1u);
        if (ticket == (unsigned)(gridDim.x - 1)) {
            const float fa = atomicAdd(&hdr[0], 0.f);
            const float fb = atomicAdd(&hdr[1], 0.f);
            const float loss = fa / (float)n;
            const float loss_seeds = fb / (float)m;
            out[0] = loss + loss_seeds;
            out[1 + m] = loss;
            out[2 + m] = loss_seeds;
        }
    }
}

extern "C" void kernel_launch(void* const* d_in, const int* in_sizes, int n_in,
                              void* d_out, int out_size, void* d_ws, size_t ws_size,
                              hipStream_t stream) {
    const int n = in_sizes[0] / 3;   // true_pos count
    const int m = in_sizes[1] / 3;   // pred_pos count
    const float* A = (const float*)d_in[0];
    const float* B = (const float*)d_in[1];
    float* out = (float*)d_out;

    const int RTn = (n + 31) / 32, RTm = (m + 31) / 32;
    char* p = (char*)d_ws;
    float*   hdr  = (float*)p;    p += 64;
    float*   sbuf = (float*)p;    p += (size_t)S_SLICES * (RTn + RTm) * 32 * 4;
    ushort8* RFA  = (ushort8*)p;  p += (size_t)RTn * 64 * 16;
    ushort8* CFA  = (ushort8*)p;  p += (size_t)RTn * 64 * 16;
    ushort8* RFB  = (ushort8*)p;  p += (size_t)RTm * 64 * 16;
    ushort8* CFB  = (ushort8*)p;

    const int maxRT = (RTn > RTm) ? RTn : RTm;
    const int maxPts = maxRT * 32;
    prep_kernel<<<(maxPts + 255) / 256, 256, 0, stream>>>(
        A, B, RFA, CFA, RFB, CFB, hdr, n, m, RTn, RTm);

    dim3 grid((maxRT + 3) / 4, S_SLICES, 2);
    pairmin_kernel<<<grid, 256, 0, stream>>>(
        (const bf16x8*)RFA, (const bf16x8*)CFA,
        (const bf16x8*)RFB, (const bf16x8*)CFB, sbuf, RTn, RTm);

    const int maxnm = (n > m) ? n : m;
    finalize_kernel<<<(maxnm + 255) / 256, 256, 0, stream>>>(
        sbuf, hdr, out, n, m, RTn, RTm);
}